// Round 5
// baseline (328.312 us; speedup 1.0000x reference)
//
#include <hip/hip_runtime.h>
#include <hip/hip_fp8.h>

#define B_ 2048
#define D_ 512
#define V_ 50304
#define NROWB 16            // 2048 / 128
#define NCOLB 393           // 50304 / 128
#define NWG (NROWB * NCOLB) // 6288 = 8 * 786
#define LOG2E 1.44269504088896340736f
#define LN2 0.69314718055994530942f

typedef __attribute__((ext_vector_type(4))) float f32x4;
typedef __attribute__((ext_vector_type(2))) unsigned long ulx2;
typedef __attribute__((ext_vector_type(8))) int v8i;
typedef unsigned char u8;

__device__ inline void gload16(const void* g, void* l) {
  __builtin_amdgcn_global_load_lds((const __attribute__((address_space(1))) void*)g,
                                   (__attribute__((address_space(3))) void*)l, 16, 0, 0);
}

// ---------------- transposing cast fp32 -> fp8 e4m3 (classifiers) ----------------
// out chunk i = ((p*4 + kk)*8 + j)*128 + c  <->  src row v=p*128+c, floats k=kk*128+j*16+[0..16)
__global__ void cast8t_kernel(const float* __restrict__ src, uint4* __restrict__ dst,
                              float scale, int nchunk) {
  int i = blockIdx.x * blockDim.x + threadIdx.x;
  if (i >= nchunk) return;
  int c = i & 127;
  int j = (i >> 7) & 7;
  int kk = (i >> 10) & 3;
  int p = i >> 12;
  const float4* s = (const float4*)(src + (size_t)(p * 128 + c) * 512 + kk * 128 + j * 16);
  union { u8 b[16]; uint4 u; } o;
#pragma unroll
  for (int q = 0; q < 4; ++q) {
    float4 f = s[q];
    o.b[q * 4 + 0] = __hip_fp8_e4m3(f.x * scale).__x;
    o.b[q * 4 + 1] = __hip_fp8_e4m3(f.y * scale).__x;
    o.b[q * 4 + 2] = __hip_fp8_e4m3(f.z * scale).__x;
    o.b[q * 4 + 3] = __hip_fp8_e4m3(f.w * scale).__x;
  }
  dst[i] = o.u;
}

// ---------------- plain cast fp32 -> fp8 e4m3 (hidden, row-major) ----------------
__global__ void cast8_kernel(const float* __restrict__ src, uint2* __restrict__ dst,
                             float scale, int n8) {
  int i = blockIdx.x * blockDim.x + threadIdx.x;
  int stride = gridDim.x * blockDim.x;
  const float4* s4 = (const float4*)src;
  for (; i < n8; i += stride) {
    float4 a = s4[2 * i], b = s4[2 * i + 1];
    union { u8 c[8]; uint2 u; } p;
    p.c[0] = __hip_fp8_e4m3(a.x * scale).__x;
    p.c[1] = __hip_fp8_e4m3(a.y * scale).__x;
    p.c[2] = __hip_fp8_e4m3(a.z * scale).__x;
    p.c[3] = __hip_fp8_e4m3(a.w * scale).__x;
    p.c[4] = __hip_fp8_e4m3(b.x * scale).__x;
    p.c[5] = __hip_fp8_e4m3(b.y * scale).__x;
    p.c[6] = __hip_fp8_e4m3(b.z * scale).__x;
    p.c[7] = __hip_fp8_e4m3(b.w * scale).__x;
    dst[i] = p.u;
  }
}

// ---------------- exact fp32 target logit (one wave per row) ----------------
__global__ void tgt_kernel(const float* __restrict__ sh, const float* __restrict__ sc,
                           const int* __restrict__ targets, float* __restrict__ tgt_out) {
  int gid = blockIdx.x * blockDim.x + threadIdx.x;
  int w = gid >> 6, lane = gid & 63;
  if (w >= B_) return;
  int tgt = targets[w];
  const float4* a = (const float4*)(sh + (size_t)w * D_);
  const float4* b = (const float4*)(sc + (size_t)tgt * D_);
  float acc = 0.f;
#pragma unroll
  for (int i = 0; i < 2; ++i) {
    float4 x = a[lane + i * 64], y = b[lane + i * 64];
    acc += x.x * y.x + x.y * y.y + x.z * y.z + x.w * y.w;
  }
#pragma unroll
  for (int off = 1; off < 64; off <<= 1) acc += __shfl_xor(acc, off);
  if (lane == 0) tgt_out[w] = acc;
}

// ---------------- fused dual-GEMM, MX-fp8 K=128, S/T wave split ----------------
// LDS per (buf,mat): fragment-linear [j(8)][col(128)][16B] = 16 KB; total 64 KB.
__global__ __launch_bounds__(256, 2) void lce_main(
    const u8* __restrict__ SH8, const u8* __restrict__ TH8,
    const u8* __restrict__ SC8t, const u8* __restrict__ TC8t,
    float* __restrict__ stats) {
  __shared__ __align__(16) u8 smem[2][2][16384];

  const int tid = threadIdx.x;
  const int lane = tid & 63, w = tid >> 6;
  const int mat = w & 1;        // 0 = student, 1 = teacher
  const int wr = w >> 1;        // row half (64 rows)
  const int rA = lane & 15;
  const int kg = lane >> 4;     // 0..3

  // XCD-aware bijective swizzle: 6288 = 8 * 786
  int hw = blockIdx.x;
  int lid = (hw & 7) * 786 + (hw >> 3);
  const int row0 = (lid & 15) * 128;
  const int p = lid >> 4;       // col panel index
  const int col0 = p * 128;

  // staging sources: contiguous 16 KB per (panel, kk), pure linear copy
  const u8* gB[2] = {SC8t + (size_t)p * 65536 + tid * 16,
                     TC8t + (size_t)p * 65536 + tid * 16};

  // A (hidden) per-lane base: row (row0+wr*64+rA+mi*16), bytes kg*32+[0..32) of each kk-chunk
  const u8* gA = (mat ? TH8 : SH8) + (size_t)(row0 + wr * 64 + rA) * D_ + kg * 32;

  f32x4 acc[4][8];
#pragma unroll
  for (int i = 0; i < 4; ++i)
#pragma unroll
    for (int j = 0; j < 8; ++j) acc[i][j] = (f32x4){0.f, 0.f, 0.f, 0.f};

  v8i av[2][4];  // double-buffered A fragments (32 B each)

#define STAGE(buf, kk)                                                        \
  {                                                                           \
    _Pragma("unroll") for (int mt = 0; mt < 2; ++mt) {                        \
      _Pragma("unroll") for (int r = 0; r < 4; ++r) {                         \
        gload16(gB[mt] + (kk) * 16384 + r * 4096,                             \
                &smem[buf][mt][r * 4096 + tid * 16]);                         \
      }                                                                       \
    }                                                                         \
  }

#define LOADA(buf, kk)                                                        \
  {                                                                           \
    _Pragma("unroll") for (int mi = 0; mi < 4; ++mi) {                        \
      av[buf][mi] = *(const v8i*)(gA + (size_t)(mi * 16) * D_ + (kk) * 128);  \
    }                                                                         \
  }

  // prologue
  STAGE(0, 0);
  LOADA(0, 0);

#pragma unroll
  for (int kk = 0; kk < 4; ++kk) {
    const int par = kk & 1;
    if (kk < 3) {
      STAGE(par ^ 1, kk + 1);
      LOADA(par ^ 1, kk + 1);
    }
    if (kk < 3)
      asm volatile("s_waitcnt vmcnt(16)\n\ts_barrier" ::: "memory");
    else
      asm volatile("s_waitcnt vmcnt(8)\n\ts_barrier" ::: "memory");

    __builtin_amdgcn_s_setprio(1);
#pragma unroll
    for (int ni = 0; ni < 8; ++ni) {
      const u8* bp = &smem[par][mat][(2 * kg) * 2048 + (ni * 16 + rA) * 16];
      union { struct { ulx2 lo, hi; } s; v8i v; } ub;
      ub.s.lo = *(const ulx2*)bp;          // j = 2*kg   -> k bytes kg*32+[0..16)
      ub.s.hi = *(const ulx2*)(bp + 2048); // j = 2*kg+1 -> k bytes kg*32+[16..32)
#pragma unroll
      for (int mi = 0; mi < 4; ++mi)
        acc[mi][ni] = __builtin_amdgcn_mfma_scale_f32_16x16x128_f8f6f4(
            av[par][mi], ub.v, acc[mi][ni], 0, 0, 0, 127, 0, 127);
    }
    __builtin_amdgcn_s_setprio(0);
    asm volatile("s_barrier" ::: "memory");
  }

  // ---------------- epilogue (identical to r4) ----------------
  const float inv = 1.0f / 256.0f;  // acc = logit * 256 * LOG2E
  float2* exch = (float2*)smem;     // [wr][mi][ni][rp][lane] float2 = 64 KB

  if (mat == 0) {
#pragma unroll
    for (int mi = 0; mi < 4; ++mi)
#pragma unroll
      for (int ni = 0; ni < 8; ++ni)
#pragma unroll
        for (int rp = 0; rp < 2; ++rp) {
          float2 v = make_float2(acc[mi][ni][2 * rp] * inv, acc[mi][ni][2 * rp + 1] * inv);
          exch[(size_t)((((wr * 4 + mi) * 8 + ni) * 2 + rp) * 64 + lane)] = v;
        }
  }
  asm volatile("s_waitcnt lgkmcnt(0)\n\ts_barrier" ::: "memory");

  if (mat == 0) {
#pragma unroll
    for (int mi = 0; mi < 4; ++mi) {
      float ssr[4] = {0.f, 0.f, 0.f, 0.f};
#pragma unroll
      for (int ni = 0; ni < 8; ++ni)
#pragma unroll
        for (int reg = 0; reg < 4; ++reg)
          ssr[reg] += __builtin_amdgcn_exp2f(acc[mi][ni][reg] * inv);
#pragma unroll
      for (int reg = 0; reg < 4; ++reg) {
        float v = ssr[reg];
#pragma unroll
        for (int off = 1; off < 16; off <<= 1) v += __shfl_xor(v, off);
        if (rA == 0)
          atomicAdd(&stats[(size_t)(row0 + wr * 64 + mi * 16 + kg * 4 + reg) * 3 + 0], v);
      }
    }
  } else {
#pragma unroll
    for (int mi = 0; mi < 4; ++mi) {
      float str[4] = {0.f, 0.f, 0.f, 0.f};
      float atr[4] = {0.f, 0.f, 0.f, 0.f};
#pragma unroll
      for (int ni = 0; ni < 8; ++ni)
#pragma unroll
        for (int rp = 0; rp < 2; ++rp) {
          float2 sv = exch[(size_t)((((wr * 4 + mi) * 8 + ni) * 2 + rp) * 64 + lane)];
          float tv0 = acc[mi][ni][2 * rp] * inv;
          float tv1 = acc[mi][ni][2 * rp + 1] * inv;
          float et0 = __builtin_amdgcn_exp2f(tv0);
          float et1 = __builtin_amdgcn_exp2f(tv1);
          str[2 * rp] += et0;
          str[2 * rp + 1] += et1;
          atr[2 * rp] += et0 * (tv0 - sv.x);
          atr[2 * rp + 1] += et1 * (tv1 - sv.y);
        }
#pragma unroll
      for (int reg = 0; reg < 4; ++reg) {
        float v = str[reg], u = atr[reg];
#pragma unroll
        for (int off = 1; off < 16; off <<= 1) {
          v += __shfl_xor(v, off);
          u += __shfl_xor(u, off);
        }
        if (rA == 0) {
          size_t r = (size_t)(row0 + wr * 64 + mi * 16 + kg * 4 + reg) * 3;
          atomicAdd(&stats[r + 1], v);
          atomicAdd(&stats[r + 2], u);
        }
      }
    }
  }
}

// ---------------- finalize: per-row loss + global sum ----------------
__global__ void finalize(const float* __restrict__ stats, const float* __restrict__ tgt,
                         const float* __restrict__ cec, const float* __restrict__ klc,
                         float* __restrict__ out) {
  __shared__ float red[16];
  int tid = threadIdx.x;  // 1024 threads
  float acc = 0.f;
  for (int r = tid; r < B_; r += 1024) {
    float ss = stats[r * 3 + 0], st = stats[r * 3 + 1], at = stats[r * 3 + 2];
    float s_lse = LN2 * __builtin_amdgcn_logf(ss);
    float t_lse = LN2 * __builtin_amdgcn_logf(st);
    float kl = s_lse - t_lse + LN2 * at / st;
    float ce = s_lse - tgt[r];
    acc += cec[r] * ce + klc[r] * kl;
  }
#pragma unroll
  for (int off = 1; off < 64; off <<= 1) acc += __shfl_xor(acc, off);
  if ((tid & 63) == 0) red[tid >> 6] = acc;
  __syncthreads();
  if (tid == 0) {
    float s = 0.f;
#pragma unroll
    for (int i = 0; i < 16; ++i) s += red[i];
    out[0] = s;
  }
}

extern "C" void kernel_launch(void* const* d_in, const int* in_sizes, int n_in,
                              void* d_out, int out_size, void* d_ws, size_t ws_size,
                              hipStream_t stream) {
  const float* sh = (const float*)d_in[0];
  const float* sc = (const float*)d_in[1];
  const float* th = (const float*)d_in[2];
  const float* tc = (const float*)d_in[3];
  const float* cec = (const float*)d_in[4];
  const float* klc = (const float*)d_in[5];
  const int* targets = (const int*)d_in[6];
  float* out = (float*)d_out;

  char* ws = (char*)d_ws;
  u8* SC8t = (u8*)ws;                               // 25,755,648 (transposed)
  u8* TC8t = SC8t + (size_t)V_ * D_;                // 25,755,648 (transposed)
  u8* SH8 = TC8t + (size_t)V_ * D_;                 // 1,048,576 (row-major)
  u8* TH8 = SH8 + (size_t)B_ * D_;                  // 1,048,576 (row-major)
  float* stats = (float*)(TH8 + (size_t)B_ * D_);   // 24 KB
  float* tgt = stats + (size_t)B_ * 3;              // 8 KB
  // total ~53.7 MB, within confirmed ws_size >= 55.7 MB

  hipMemsetAsync(stats, 0, (size_t)B_ * 3 * sizeof(float), stream);
  const float hscale = 16.0f * LOG2E;
  const float cscale = 16.0f;
  const int nchunk = V_ * D_ / 16;  // 1,609,728
  cast8t_kernel<<<(nchunk + 255) / 256, 256, 0, stream>>>(sc, (uint4*)SC8t, cscale, nchunk);
  cast8t_kernel<<<(nchunk + 255) / 256, 256, 0, stream>>>(tc, (uint4*)TC8t, cscale, nchunk);
  cast8_kernel<<<256, 256, 0, stream>>>(sh, (uint2*)SH8, hscale, B_ * D_ / 8);
  cast8_kernel<<<256, 256, 0, stream>>>(th, (uint2*)TH8, hscale, B_ * D_ / 8);
  tgt_kernel<<<512, 256, 0, stream>>>(sh, sc, targets, tgt);

  lce_main<<<NWG, 256, 0, stream>>>(SH8, TH8, SC8t, TC8t, stats);
  finalize<<<1, 1024, 0, stream>>>(stats, tgt, cec, klc, out);
}

// Round 6
// 292.449 us; speedup vs baseline: 1.1226x; 1.1226x over previous
//
#include <hip/hip_runtime.h>
#include <hip/hip_fp8.h>

#define B_ 2048
#define D_ 512
#define V_ 50304
#define NROWB 16            // 2048 / 128
#define NCOLB 393           // 50304 / 128
#define NWG (NROWB * NCOLB) // 6288 = 8 * 786
#define NCOPY 32
#define LOG2E 1.44269504088896340736f
#define LN2 0.69314718055994530942f

typedef __attribute__((ext_vector_type(4))) float f32x4;
typedef __attribute__((ext_vector_type(2))) unsigned long ulx2;
typedef __attribute__((ext_vector_type(8))) int v8i;
typedef unsigned char u8;

__device__ inline void gload16(const void* g, void* l) {
  __builtin_amdgcn_global_load_lds((const __attribute__((address_space(1))) void*)g,
                                   (__attribute__((address_space(3))) void*)l, 16, 0, 0);
}

// ---------------- transposing cast fp32 -> fp8 e4m3 (classifiers) ----------------
// out chunk i = ((p*4 + kk)*8 + j)*128 + c  <->  src row v=p*128+c, floats k=kk*128+j*16+[0..16)
__global__ void cast8t_kernel(const float* __restrict__ src, uint4* __restrict__ dst,
                              float scale, int nchunk) {
  int i = blockIdx.x * blockDim.x + threadIdx.x;
  if (i >= nchunk) return;
  int c = i & 127;
  int j = (i >> 7) & 7;
  int kk = (i >> 10) & 3;
  int p = i >> 12;
  const float4* s = (const float4*)(src + (size_t)(p * 128 + c) * 512 + kk * 128 + j * 16);
  union { u8 b[16]; uint4 u; } o;
#pragma unroll
  for (int q = 0; q < 4; ++q) {
    float4 f = s[q];
    o.b[q * 4 + 0] = __hip_fp8_e4m3(f.x * scale).__x;
    o.b[q * 4 + 1] = __hip_fp8_e4m3(f.y * scale).__x;
    o.b[q * 4 + 2] = __hip_fp8_e4m3(f.z * scale).__x;
    o.b[q * 4 + 3] = __hip_fp8_e4m3(f.w * scale).__x;
  }
  dst[i] = o.u;
}

// ---------------- plain cast fp32 -> fp8 e4m3 (hidden, row-major) ----------------
__global__ void cast8_kernel(const float* __restrict__ src, uint2* __restrict__ dst,
                             float scale, int n8) {
  int i = blockIdx.x * blockDim.x + threadIdx.x;
  int stride = gridDim.x * blockDim.x;
  const float4* s4 = (const float4*)src;
  for (; i < n8; i += stride) {
    float4 a = s4[2 * i], b = s4[2 * i + 1];
    union { u8 c[8]; uint2 u; } p;
    p.c[0] = __hip_fp8_e4m3(a.x * scale).__x;
    p.c[1] = __hip_fp8_e4m3(a.y * scale).__x;
    p.c[2] = __hip_fp8_e4m3(a.z * scale).__x;
    p.c[3] = __hip_fp8_e4m3(a.w * scale).__x;
    p.c[4] = __hip_fp8_e4m3(b.x * scale).__x;
    p.c[5] = __hip_fp8_e4m3(b.y * scale).__x;
    p.c[6] = __hip_fp8_e4m3(b.z * scale).__x;
    p.c[7] = __hip_fp8_e4m3(b.w * scale).__x;
    dst[i] = p.u;
  }
}

// ---------------- exact fp32 target logit (one wave per row) ----------------
__global__ void tgt_kernel(const float* __restrict__ sh, const float* __restrict__ sc,
                           const int* __restrict__ targets, float* __restrict__ tgt_out) {
  int gid = blockIdx.x * blockDim.x + threadIdx.x;
  int w = gid >> 6, lane = gid & 63;
  if (w >= B_) return;
  int tgt = targets[w];
  const float4* a = (const float4*)(sh + (size_t)w * D_);
  const float4* b = (const float4*)(sc + (size_t)tgt * D_);
  float acc = 0.f;
#pragma unroll
  for (int i = 0; i < 2; ++i) {
    float4 x = a[lane + i * 64], y = b[lane + i * 64];
    acc += x.x * y.x + x.y * y.y + x.z * y.z + x.w * y.w;
  }
#pragma unroll
  for (int off = 1; off < 64; off <<= 1) acc += __shfl_xor(acc, off);
  if (lane == 0) tgt_out[w] = acc;
}

// ---------------- fused dual-GEMM, MX-fp8 K=128, S/T wave split ----------------
// LDS per (buf,mat): fragment-linear [j(8)][col(128)][16B] = 16 KB; total 64 KB.
// Epilogue: XCD-local spread accumulators (32 copies) to kill atomic contention.
__global__ __launch_bounds__(256, 2) void lce_main(
    const u8* __restrict__ SH8, const u8* __restrict__ TH8,
    const u8* __restrict__ SC8t, const u8* __restrict__ TC8t,
    float* __restrict__ stats32) {
  __shared__ __align__(16) u8 smem[2][2][16384];

  const int tid = threadIdx.x;
  const int lane = tid & 63, w = tid >> 6;
  const int mat = w & 1;        // 0 = student, 1 = teacher
  const int wr = w >> 1;        // row half (64 rows)
  const int rA = lane & 15;
  const int kg = lane >> 4;     // 0..3

  // XCD-aware bijective swizzle: 6288 = 8 * 786; lid = xcd*786 + seq
  int hw = blockIdx.x;
  int lid = (hw & 7) * 786 + (hw >> 3);
  const int row0 = (lid & 15) * 128;
  const int p = lid >> 4;       // col panel index
  // accumulator copy: XCD-local (no cross-XCD line migration), panel-spread within XCD
  const int jcopy = (hw & 7) * 4 + ((lid >> 4) & 3);
  float* stats = stats32 + (size_t)jcopy * B_ * 3;

  // staging sources: contiguous 16 KB per (panel, kk), pure linear copy
  const u8* gB[2] = {SC8t + (size_t)p * 65536 + tid * 16,
                     TC8t + (size_t)p * 65536 + tid * 16};

  // A (hidden) per-lane base: row (row0+wr*64+rA+mi*16), bytes kg*32+[0..32) of each kk-chunk
  const u8* gA = (mat ? TH8 : SH8) + (size_t)(row0 + wr * 64 + rA) * D_ + kg * 32;

  f32x4 acc[4][8];
#pragma unroll
  for (int i = 0; i < 4; ++i)
#pragma unroll
    for (int j = 0; j < 8; ++j) acc[i][j] = (f32x4){0.f, 0.f, 0.f, 0.f};

  v8i av[2][4];  // double-buffered A fragments (32 B each)

#define STAGE(buf, kk)                                                        \
  {                                                                           \
    _Pragma("unroll") for (int mt = 0; mt < 2; ++mt) {                        \
      _Pragma("unroll") for (int r = 0; r < 4; ++r) {                         \
        gload16(gB[mt] + (kk) * 16384 + r * 4096,                             \
                &smem[buf][mt][r * 4096 + tid * 16]);                         \
      }                                                                       \
    }                                                                         \
  }

#define LOADA(buf, kk)                                                        \
  {                                                                           \
    _Pragma("unroll") for (int mi = 0; mi < 4; ++mi) {                        \
      av[buf][mi] = *(const v8i*)(gA + (size_t)(mi * 16) * D_ + (kk) * 128);  \
    }                                                                         \
  }

  // prologue
  STAGE(0, 0);
  LOADA(0, 0);

#pragma unroll
  for (int kk = 0; kk < 4; ++kk) {
    const int par = kk & 1;
    if (kk < 3) {
      STAGE(par ^ 1, kk + 1);
      LOADA(par ^ 1, kk + 1);
    }
    if (kk < 3)
      asm volatile("s_waitcnt vmcnt(16)\n\ts_barrier" ::: "memory");
    else
      asm volatile("s_waitcnt vmcnt(8)\n\ts_barrier" ::: "memory");

    __builtin_amdgcn_s_setprio(1);
#pragma unroll
    for (int ni = 0; ni < 8; ++ni) {
      const u8* bp = &smem[par][mat][(2 * kg) * 2048 + (ni * 16 + rA) * 16];
      union { struct { ulx2 lo, hi; } s; v8i v; } ub;
      ub.s.lo = *(const ulx2*)bp;          // j = 2*kg   -> k bytes kg*32+[0..16)
      ub.s.hi = *(const ulx2*)(bp + 2048); // j = 2*kg+1 -> k bytes kg*32+[16..32)
#pragma unroll
      for (int mi = 0; mi < 4; ++mi)
        acc[mi][ni] = __builtin_amdgcn_mfma_scale_f32_16x16x128_f8f6f4(
            av[par][mi], ub.v, acc[mi][ni], 0, 0, 0, 127, 0, 127);
    }
    __builtin_amdgcn_s_setprio(0);
    asm volatile("s_barrier" ::: "memory");
  }

  // ---------------- epilogue ----------------
  const float inv = 1.0f / 256.0f;  // acc = logit * 256 * LOG2E
  float2* exch = (float2*)smem;     // [wr][mi][ni][rp][lane] float2 = 64 KB

  if (mat == 0) {
#pragma unroll
    for (int mi = 0; mi < 4; ++mi)
#pragma unroll
      for (int ni = 0; ni < 8; ++ni)
#pragma unroll
        for (int rp = 0; rp < 2; ++rp) {
          float2 v = make_float2(acc[mi][ni][2 * rp] * inv, acc[mi][ni][2 * rp + 1] * inv);
          exch[(size_t)((((wr * 4 + mi) * 8 + ni) * 2 + rp) * 64 + lane)] = v;
        }
  }
  asm volatile("s_waitcnt lgkmcnt(0)\n\ts_barrier" ::: "memory");

  if (mat == 0) {
#pragma unroll
    for (int mi = 0; mi < 4; ++mi) {
      float ssr[4] = {0.f, 0.f, 0.f, 0.f};
#pragma unroll
      for (int ni = 0; ni < 8; ++ni)
#pragma unroll
        for (int reg = 0; reg < 4; ++reg)
          ssr[reg] += __builtin_amdgcn_exp2f(acc[mi][ni][reg] * inv);
#pragma unroll
      for (int reg = 0; reg < 4; ++reg) {
        float v = ssr[reg];
#pragma unroll
        for (int off = 1; off < 16; off <<= 1) v += __shfl_xor(v, off);
        if (rA == 0)
          atomicAdd(&stats[(size_t)(row0 + wr * 64 + mi * 16 + kg * 4 + reg) * 3 + 0], v);
      }
    }
  } else {
#pragma unroll
    for (int mi = 0; mi < 4; ++mi) {
      float str[4] = {0.f, 0.f, 0.f, 0.f};
      float atr[4] = {0.f, 0.f, 0.f, 0.f};
#pragma unroll
      for (int ni = 0; ni < 8; ++ni)
#pragma unroll
        for (int rp = 0; rp < 2; ++rp) {
          float2 sv = exch[(size_t)((((wr * 4 + mi) * 8 + ni) * 2 + rp) * 64 + lane)];
          float tv0 = acc[mi][ni][2 * rp] * inv;
          float tv1 = acc[mi][ni][2 * rp + 1] * inv;
          float et0 = __builtin_amdgcn_exp2f(tv0);
          float et1 = __builtin_amdgcn_exp2f(tv1);
          str[2 * rp] += et0;
          str[2 * rp + 1] += et1;
          atr[2 * rp] += et0 * (tv0 - sv.x);
          atr[2 * rp + 1] += et1 * (tv1 - sv.y);
        }
#pragma unroll
      for (int reg = 0; reg < 4; ++reg) {
        float v = str[reg], u = atr[reg];
#pragma unroll
        for (int off = 1; off < 16; off <<= 1) {
          v += __shfl_xor(v, off);
          u += __shfl_xor(u, off);
        }
        if (rA == 0) {
          size_t r = (size_t)(row0 + wr * 64 + mi * 16 + kg * 4 + reg) * 3;
          atomicAdd(&stats[r + 1], v);
          atomicAdd(&stats[r + 2], u);
        }
      }
    }
  }
}

// ---------------- finalize: sum spread copies, per-row loss + global sum ----------------
__global__ void finalize(const float* __restrict__ stats32, const float* __restrict__ tgt,
                         const float* __restrict__ cec, const float* __restrict__ klc,
                         float* __restrict__ out) {
  __shared__ float red[16];
  int tid = threadIdx.x;  // 1024 threads
  float acc = 0.f;
  for (int r = tid; r < B_; r += 1024) {
    float ss = 0.f, st = 0.f, at = 0.f;
#pragma unroll
    for (int j = 0; j < NCOPY; ++j) {
      const float* s = stats32 + ((size_t)j * B_ + r) * 3;
      ss += s[0]; st += s[1]; at += s[2];
    }
    float s_lse = LN2 * __builtin_amdgcn_logf(ss);
    float t_lse = LN2 * __builtin_amdgcn_logf(st);
    float kl = s_lse - t_lse + LN2 * at / st;
    float ce = s_lse - tgt[r];
    acc += cec[r] * ce + klc[r] * kl;
  }
#pragma unroll
  for (int off = 1; off < 64; off <<= 1) acc += __shfl_xor(acc, off);
  if ((tid & 63) == 0) red[tid >> 6] = acc;
  __syncthreads();
  if (tid == 0) {
    float s = 0.f;
#pragma unroll
    for (int i = 0; i < 16; ++i) s += red[i];
    out[0] = s;
  }
}

extern "C" void kernel_launch(void* const* d_in, const int* in_sizes, int n_in,
                              void* d_out, int out_size, void* d_ws, size_t ws_size,
                              hipStream_t stream) {
  const float* sh = (const float*)d_in[0];
  const float* sc = (const float*)d_in[1];
  const float* th = (const float*)d_in[2];
  const float* tc = (const float*)d_in[3];
  const float* cec = (const float*)d_in[4];
  const float* klc = (const float*)d_in[5];
  const int* targets = (const int*)d_in[6];
  float* out = (float*)d_out;

  char* ws = (char*)d_ws;
  u8* SC8t = (u8*)ws;                               // 25,755,648 (transposed)
  u8* TC8t = SC8t + (size_t)V_ * D_;                // 25,755,648 (transposed)
  u8* SH8 = TC8t + (size_t)V_ * D_;                 // 1,048,576 (row-major)
  u8* TH8 = SH8 + (size_t)B_ * D_;                  // 1,048,576 (row-major)
  float* stats32 = (float*)(TH8 + (size_t)B_ * D_); // 786,432 B: [32][2048][3]
  float* tgt = stats32 + (size_t)NCOPY * B_ * 3;    // 8 KB
  // total ~54.4 MB, within confirmed ws_size >= 55.7 MB

  hipMemsetAsync(stats32, 0, (size_t)NCOPY * B_ * 3 * sizeof(float), stream);
  const float hscale = 16.0f * LOG2E;
  const float cscale = 16.0f;
  const int nchunk = V_ * D_ / 16;  // 1,609,728
  cast8t_kernel<<<(nchunk + 255) / 256, 256, 0, stream>>>(sc, (uint4*)SC8t, cscale, nchunk);
  cast8t_kernel<<<(nchunk + 255) / 256, 256, 0, stream>>>(tc, (uint4*)TC8t, cscale, nchunk);
  cast8_kernel<<<256, 256, 0, stream>>>(sh, (uint2*)SH8, hscale, B_ * D_ / 8);
  cast8_kernel<<<256, 256, 0, stream>>>(th, (uint2*)TH8, hscale, B_ * D_ / 8);
  tgt_kernel<<<512, 256, 0, stream>>>(sh, sc, targets, tgt);

  lce_main<<<NWG, 256, 0, stream>>>(SH8, TH8, SC8t, TC8t, stats32);
  finalize<<<1, 1024, 0, stream>>>(stats32, tgt, cec, klc, out);
}